// Round 2
// 6504.243 us; speedup vs baseline: 1.4407x; 1.4407x over previous
//
#include <hip/hip_runtime.h>
#include <math.h>

// ESN recurrence: x_t = tanh(u_t @ w_in^T + w_bias + W @ h_{t-1}), h_0 = 0.
// B=8, T=4096, D_RES=1024, D_IN=64, fp32.
//
// R4 (= R3 fixed): R3's tag-in-data exchange removed the counter-barrier
// chain, but it also removed LDS staging, so every thread loaded all 32 of
// its k-slice h elements straight from the coherence point: 16 MB/step of
// sc-bypassing traffic (16x R2), amplified by spin retries -> IC congestion,
// likely the cause of the harness failure.
//
// R4 keeps tag-in-data but restores LDS staging:
//   - producer publishes each h element as ONE 8-byte relaxed agent atomic:
//     hi32 = step tag (t+1), lo32 = float bits. Validity travels WITH data.
//   - consumer WG loads each element ONCE (4 tagged u64 loads per thread,
//     8 KB/WG/step -- same cross-WG traffic as R2), spins (rarely) on its
//     own 4 tags only, stages floats into LDS, one intra-WG __syncthreads,
//     then computes from LDS exactly like R2.
//   - LDS double-buffered on (t&1): the write-after-read hazard on buffer
//     (t&1) is separated by iteration t+1's barrier in program order, so
//     ONE barrier per step suffices (vs 3 in R2).
// Removed entirely vs R2: arrival atomics on a hot line, sleep-quantized
// polling of the counter, 2 of 3 barriers, the separate drain->flag->poll->
// reload chain.
//
// Safety: WG C publishes x_t only after its barrier, i.e. after ALL of C's
// threads consumed x_{t-1}. Any producer P overwrites a slot with x_{t+1}
// only after reading all of x_t, which requires every WG to have published
// x_t, which requires every WG to have consumed x_{t-1}. So no slot is
// overwritten while any WG still needs it, and observed tags during step t
// never exceed t. Tags are monotonic; hbuf is zeroed per launch.

#define NB        8
#define T_STEPS   4096
#define DRES      1024
#define DIN       64
#define NTHREADS  256

typedef unsigned long long u64;

#define HBUF_BYTES (2 * NB * DRES * sizeof(u64))   // 128 KB, zeroed per launch

__launch_bounds__(NTHREADS, 1)
__global__ void esn_kernel(const float* __restrict__ u,      // [NB][T][DIN]
                           const float* __restrict__ w_in,   // [DRES][DIN]
                           const float* __restrict__ w,      // [DRES][DRES]
                           const float* __restrict__ w_bias, // [DRES]
                           float* __restrict__ out,          // [NB][T][DRES]
                           u64* __restrict__ hbuf)           // [2][NB][DRES] (tag|bits)
{
    const int tid   = threadIdx.x;
    const int b     = (int)blockIdx.x & (NB - 1);   // batch -> XCD affinity heuristic
    const int chunk = (int)blockIdx.x >> 3;         // 0..31 row-chunk
    const int rg    = tid >> 5;                     // 0..7 row-group (4 rows each)
    const int mc    = tid & 31;                     // 0..31 k-lane
    const int row0  = chunk * 32 + rg * 4;          // first of this thread's 4 rows

    __shared__ float h_lds[2][DRES];                // double-buffered h stage

    // ---- prologue: weights into registers ----
    float wreg[4][32];                              // wreg[i][j] = W[row0+i][mc+32j]
    #pragma unroll
    for (int i = 0; i < 4; ++i) {
        const float* wr = w + (size_t)(row0 + i) * DRES + mc;
        #pragma unroll
        for (int j = 0; j < 32; ++j) {
            wreg[i][j] = wr[32 * j];
        }
    }
    float win0[4], win1[4], bias[4];
    #pragma unroll
    for (int i = 0; i < 4; ++i) {
        win0[i] = w_in[(row0 + i) * DIN + 2 * mc];
        win1[i] = w_in[(row0 + i) * DIN + 2 * mc + 1];
        bias[i] = w_bias[row0 + i];
    }

    const float* ub = u + (size_t)b * T_STEPS * DIN;
    u64* const hb0 = hbuf + (size_t)b * DRES;            // slot for even t
    u64* const hb1 = hbuf + (size_t)(NB + b) * DRES;     // slot for odd t

    float2 ucur = *(const float2*)(ub + 2 * mc);

    // ---- t = 0 peeled: h_0 = 0, recurrent term vanishes ----
    {
        const float2 unext = *(const float2*)(ub + DIN + 2 * mc);
        float acc[4];
        #pragma unroll
        for (int i = 0; i < 4; ++i) {
            acc[i] = fmaf(win0[i], ucur.x, win1[i] * ucur.y);
        }
        #pragma unroll
        for (int d = 1; d < 32; d <<= 1) {
            #pragma unroll
            for (int i = 0; i < 4; ++i) {
                acc[i] += __shfl_xor(acc[i], d, 64);
            }
        }
        float x[4];
        #pragma unroll
        for (int i = 0; i < 4; ++i) {
            const float z = acc[i] + bias[i];
            const float e = __expf(2.0f * z);
            x[i] = 1.0f - 2.0f / (e + 1.0f);
        }
        // publish first (latency-critical), then the cached out store
        if (mc < 4) {
            const float v = (mc & 2) ? ((mc & 1) ? x[3] : x[2])
                                     : ((mc & 1) ? x[1] : x[0]);
            __hip_atomic_store(hb0 + row0 + mc,
                               ((u64)1u << 32) | (u64)__float_as_uint(v),
                               __ATOMIC_RELAXED, __HIP_MEMORY_SCOPE_AGENT);
        }
        if (mc == 0) {
            *(float4*)(out + (size_t)b * T_STEPS * DRES + row0) =
                make_float4(x[0], x[1], x[2], x[3]);
        }
        ucur = unext;
    }

    #pragma unroll 1
    for (int t = 1; t < T_STEPS; ++t) {
        u64* const hs = (t & 1) ? hb0 : hb1;      // slot holding x_{t-1} (tag t)
        u64* const hp = (t & 1) ? hb1 : hb0;      // slot for x_t (tag t+1)

        // each thread loads its 4 tagged h elements (WG covers 0..1023 once)
        u64 hv[4];
        #pragma unroll
        for (int i = 0; i < 4; ++i) {
            hv[i] = __hip_atomic_load(hs + tid + 256 * i,
                                      __ATOMIC_RELAXED, __HIP_MEMORY_SCOPE_AGENT);
        }

        const int tn = (t + 1 < T_STEPS) ? (t + 1) : t;
        const float2 unext = *(const float2*)(ub + (size_t)tn * DIN + 2 * mc);

        // input projection overlaps the in-flight tagged loads
        float acc[4];
        #pragma unroll
        for (int i = 0; i < 4; ++i) {
            acc[i] = fmaf(win0[i], ucur.x, win1[i] * ucur.y);
        }

        // validate tags; spin (rare) reloading only this thread's 4 elements
        {
            const unsigned tgt = (unsigned)t;
            unsigned mn = 0xFFFFFFFFu;
            #pragma unroll
            for (int i = 0; i < 4; ++i) {
                const unsigned tg = (unsigned)(hv[i] >> 32);
                mn = tg < mn ? tg : mn;
            }
            int tries = 0;
            while (mn < tgt) {
                if (tries++ > 0) __builtin_amdgcn_s_sleep(1);
                mn = 0xFFFFFFFFu;
                #pragma unroll
                for (int i = 0; i < 4; ++i) {
                    hv[i] = __hip_atomic_load(hs + tid + 256 * i,
                                              __ATOMIC_RELAXED, __HIP_MEMORY_SCOPE_AGENT);
                    const unsigned tg = (unsigned)(hv[i] >> 32);
                    mn = tg < mn ? tg : mn;
                }
            }
        }

        // stage into LDS (double-buffered: WAR on this buffer is separated
        // by iteration t+1's barrier in program order)
        float* const hl = h_lds[t & 1];
        #pragma unroll
        for (int i = 0; i < 4; ++i) {
            hl[tid + 256 * i] = __uint_as_float((unsigned)hv[i]);
        }
        __syncthreads();

        // recurrent matvec: W in regs, h broadcast from LDS
        #pragma unroll
        for (int j = 0; j < 32; ++j) {
            const float hvf = hl[mc + 32 * j];
            #pragma unroll
            for (int i = 0; i < 4; ++i) {
                acc[i] = fmaf(wreg[i][j], hvf, acc[i]);
            }
        }

        // butterfly reduce across the 32 k-lanes (stays within 32-lane halves)
        #pragma unroll
        for (int d = 1; d < 32; d <<= 1) {
            #pragma unroll
            for (int i = 0; i < 4; ++i) {
                acc[i] += __shfl_xor(acc[i], d, 64);
            }
        }

        float x[4];
        #pragma unroll
        for (int i = 0; i < 4; ++i) {
            const float z = acc[i] + bias[i];
            const float e = __expf(2.0f * z);
            x[i] = 1.0f - 2.0f / (e + 1.0f);
        }

        // publish tagged h first (latency-critical path to consumers)
        if (t + 1 < T_STEPS && mc < 4) {
            const float v = (mc & 2) ? ((mc & 1) ? x[3] : x[2])
                                     : ((mc & 1) ? x[1] : x[0]);
            __hip_atomic_store(hp + row0 + mc,
                               ((u64)(unsigned)(t + 1) << 32) | (u64)__float_as_uint(v),
                               __ATOMIC_RELAXED, __HIP_MEMORY_SCOPE_AGENT);
        }
        // output store: normal cached path (nobody reads it; L2 writes back lazily)
        if (mc == 0) {
            *(float4*)(out + ((size_t)b * T_STEPS + t) * DRES + row0) =
                make_float4(x[0], x[1], x[2], x[3]);
        }

        ucur = unext;
    }
}

extern "C" void kernel_launch(void* const* d_in, const int* in_sizes, int n_in,
                              void* d_out, int out_size, void* d_ws, size_t ws_size,
                              hipStream_t stream) {
    const float* u      = (const float*)d_in[0];
    const float* w_in   = (const float*)d_in[1];
    const float* w      = (const float*)d_in[2];
    const float* w_bias = (const float*)d_in[3];
    float* out = (float*)d_out;
    u64* hbuf = (u64*)d_ws;

    // tags must start below 1 (ws is re-poisoned before every call)
    hipMemsetAsync(hbuf, 0, HBUF_BYTES, stream);

    esn_kernel<<<NB * 32, NTHREADS, 0, stream>>>(u, w_in, w, w_bias, out, hbuf);
}

// Round 3
// 6244.633 us; speedup vs baseline: 1.5006x; 1.0416x over previous
//
#include <hip/hip_runtime.h>
#include <math.h>

// ESN recurrence: x_t = tanh(u_t @ w_in^T + w_bias + W @ h_{t-1}), h_0 = 0.
// B=8, T=4096, D_RES=1024, D_IN=64, fp32.
//
// R5 change vs R4: the 32-lane butterfly reduce used __shfl_xor x20
// (5 dependent rounds x 4 accumulators), lowering to DS-pipe ops with a
// dependent ~100cy round trip each -> ~450-600 cy of the 3800-cy step, paid
// on the critical publish path. Replaced with a numerics-IDENTICAL hybrid:
//   xor1  -> DPP quad_perm[1,0,3,2] (0xB1)        ~4 cy VALU
//   xor2  -> DPP quad_perm[2,3,0,1] (0x4E)        ~4 cy VALU
//   xor4  -> DPP ROW_HALF_MIRROR (0x141): after rounds 1-2 each quad is
//            value-uniform, so lane l^7 == lane l^4 bit-exactly
//   xor8  -> DPP ROW_MIRROR (0x140): octet-uniform, lane l^15 == lane l^8
//   xor16 -> single ds_swizzle 0x401F (lane^16 within each 32-half, same
//            as __shfl_xor(x,16,64))
// Only 1 DS round remains instead of 5. Same pairwise summation tree ->
// bit-identical results (absmax must stay 0.00390625).
//
// Sync protocol unchanged from R4 (tag-in-data): producer publishes each h
// element as one 8-byte relaxed agent atomic (hi32 = step tag t+1, lo32 =
// float bits); consumer loads each element once, spins rarely on its own 4
// tags, stages into double-buffered LDS, ONE barrier per step.
//
// Safety (unchanged): WG C publishes x_t only after all its threads
// consumed x_{t-1}; producer overwrites a slot with x_{t+1} only after
// reading all of x_t, which requires every WG to have published x_t, which
// requires every WG consumed x_{t-1}. Tags monotonic; hbuf zeroed per launch.

#define NB        8
#define T_STEPS   4096
#define DRES      1024
#define DIN       64
#define NTHREADS  256

typedef unsigned long long u64;

#define HBUF_BYTES (2 * NB * DRES * sizeof(u64))   // 128 KB, zeroed per launch

// Butterfly sum over 32 lanes, bit-identical to the 5-round __shfl_xor tree.
__device__ __forceinline__ float bfly32(float v) {
    v += __int_as_float(__builtin_amdgcn_update_dpp(
            0, __float_as_int(v), 0xB1, 0xF, 0xF, true));   // xor1 (quad_perm)
    v += __int_as_float(__builtin_amdgcn_update_dpp(
            0, __float_as_int(v), 0x4E, 0xF, 0xF, true));   // xor2 (quad_perm)
    v += __int_as_float(__builtin_amdgcn_update_dpp(
            0, __float_as_int(v), 0x141, 0xF, 0xF, true));  // xor4 via half_mirror
    v += __int_as_float(__builtin_amdgcn_update_dpp(
            0, __float_as_int(v), 0x140, 0xF, 0xF, true));  // xor8 via mirror
    v += __int_as_float(__builtin_amdgcn_ds_swizzle(
            __float_as_int(v), 0x401F));                    // xor16
    return v;
}

__launch_bounds__(NTHREADS, 1)
__global__ void esn_kernel(const float* __restrict__ u,      // [NB][T][DIN]
                           const float* __restrict__ w_in,   // [DRES][DIN]
                           const float* __restrict__ w,      // [DRES][DRES]
                           const float* __restrict__ w_bias, // [DRES]
                           float* __restrict__ out,          // [NB][T][DRES]
                           u64* __restrict__ hbuf)           // [2][NB][DRES] (tag|bits)
{
    const int tid   = threadIdx.x;
    const int b     = (int)blockIdx.x & (NB - 1);   // batch -> XCD affinity heuristic
    const int chunk = (int)blockIdx.x >> 3;         // 0..31 row-chunk
    const int rg    = tid >> 5;                     // 0..7 row-group (4 rows each)
    const int mc    = tid & 31;                     // 0..31 k-lane
    const int row0  = chunk * 32 + rg * 4;          // first of this thread's 4 rows

    __shared__ float h_lds[2][DRES];                // double-buffered h stage

    // ---- prologue: weights into registers ----
    float wreg[4][32];                              // wreg[i][j] = W[row0+i][mc+32j]
    #pragma unroll
    for (int i = 0; i < 4; ++i) {
        const float* wr = w + (size_t)(row0 + i) * DRES + mc;
        #pragma unroll
        for (int j = 0; j < 32; ++j) {
            wreg[i][j] = wr[32 * j];
        }
    }
    float win0[4], win1[4], bias[4];
    #pragma unroll
    for (int i = 0; i < 4; ++i) {
        win0[i] = w_in[(row0 + i) * DIN + 2 * mc];
        win1[i] = w_in[(row0 + i) * DIN + 2 * mc + 1];
        bias[i] = w_bias[row0 + i];
    }

    const float* ub = u + (size_t)b * T_STEPS * DIN;
    u64* const hb0 = hbuf + (size_t)b * DRES;            // slot for even t
    u64* const hb1 = hbuf + (size_t)(NB + b) * DRES;     // slot for odd t

    float2 ucur = *(const float2*)(ub + 2 * mc);

    // ---- t = 0 peeled: h_0 = 0, recurrent term vanishes ----
    {
        const float2 unext = *(const float2*)(ub + DIN + 2 * mc);
        float acc[4];
        #pragma unroll
        for (int i = 0; i < 4; ++i) {
            acc[i] = fmaf(win0[i], ucur.x, win1[i] * ucur.y);
        }
        #pragma unroll
        for (int i = 0; i < 4; ++i) {
            acc[i] = bfly32(acc[i]);
        }
        float x[4];
        #pragma unroll
        for (int i = 0; i < 4; ++i) {
            const float z = acc[i] + bias[i];
            const float e = __expf(2.0f * z);
            x[i] = 1.0f - 2.0f / (e + 1.0f);
        }
        // publish first (latency-critical), then the cached out store
        if (mc < 4) {
            const float v = (mc & 2) ? ((mc & 1) ? x[3] : x[2])
                                     : ((mc & 1) ? x[1] : x[0]);
            __hip_atomic_store(hb0 + row0 + mc,
                               ((u64)1u << 32) | (u64)__float_as_uint(v),
                               __ATOMIC_RELAXED, __HIP_MEMORY_SCOPE_AGENT);
        }
        if (mc == 0) {
            *(float4*)(out + (size_t)b * T_STEPS * DRES + row0) =
                make_float4(x[0], x[1], x[2], x[3]);
        }
        ucur = unext;
    }

    #pragma unroll 1
    for (int t = 1; t < T_STEPS; ++t) {
        u64* const hs = (t & 1) ? hb0 : hb1;      // slot holding x_{t-1} (tag t)
        u64* const hp = (t & 1) ? hb1 : hb0;      // slot for x_t (tag t+1)

        // each thread loads its 4 tagged h elements (WG covers 0..1023 once)
        u64 hv[4];
        #pragma unroll
        for (int i = 0; i < 4; ++i) {
            hv[i] = __hip_atomic_load(hs + tid + 256 * i,
                                      __ATOMIC_RELAXED, __HIP_MEMORY_SCOPE_AGENT);
        }

        const int tn = (t + 1 < T_STEPS) ? (t + 1) : t;
        const float2 unext = *(const float2*)(ub + (size_t)tn * DIN + 2 * mc);

        // input projection overlaps the in-flight tagged loads
        float acc[4];
        #pragma unroll
        for (int i = 0; i < 4; ++i) {
            acc[i] = fmaf(win0[i], ucur.x, win1[i] * ucur.y);
        }

        // validate tags; spin (rare) reloading only this thread's 4 elements
        {
            const unsigned tgt = (unsigned)t;
            unsigned mn = 0xFFFFFFFFu;
            #pragma unroll
            for (int i = 0; i < 4; ++i) {
                const unsigned tg = (unsigned)(hv[i] >> 32);
                mn = tg < mn ? tg : mn;
            }
            int tries = 0;
            while (mn < tgt) {
                if (tries++ > 0) __builtin_amdgcn_s_sleep(1);
                mn = 0xFFFFFFFFu;
                #pragma unroll
                for (int i = 0; i < 4; ++i) {
                    hv[i] = __hip_atomic_load(hs + tid + 256 * i,
                                              __ATOMIC_RELAXED, __HIP_MEMORY_SCOPE_AGENT);
                    const unsigned tg = (unsigned)(hv[i] >> 32);
                    mn = tg < mn ? tg : mn;
                }
            }
        }

        // stage into LDS (double-buffered: WAR on this buffer is separated
        // by iteration t+1's barrier in program order)
        float* const hl = h_lds[t & 1];
        #pragma unroll
        for (int i = 0; i < 4; ++i) {
            hl[tid + 256 * i] = __uint_as_float((unsigned)hv[i]);
        }
        __syncthreads();

        // recurrent matvec: W in regs, h broadcast from LDS
        #pragma unroll
        for (int j = 0; j < 32; ++j) {
            const float hvf = hl[mc + 32 * j];
            #pragma unroll
            for (int i = 0; i < 4; ++i) {
                acc[i] = fmaf(wreg[i][j], hvf, acc[i]);
            }
        }

        // butterfly reduce across the 32 k-lanes (DPP + 1 ds_swizzle;
        // bit-identical to the old 5-round __shfl_xor tree)
        #pragma unroll
        for (int i = 0; i < 4; ++i) {
            acc[i] = bfly32(acc[i]);
        }

        float x[4];
        #pragma unroll
        for (int i = 0; i < 4; ++i) {
            const float z = acc[i] + bias[i];
            const float e = __expf(2.0f * z);
            x[i] = 1.0f - 2.0f / (e + 1.0f);
        }

        // publish tagged h first (latency-critical path to consumers)
        if (t + 1 < T_STEPS && mc < 4) {
            const float v = (mc & 2) ? ((mc & 1) ? x[3] : x[2])
                                     : ((mc & 1) ? x[1] : x[0]);
            __hip_atomic_store(hp + row0 + mc,
                               ((u64)(unsigned)(t + 1) << 32) | (u64)__float_as_uint(v),
                               __ATOMIC_RELAXED, __HIP_MEMORY_SCOPE_AGENT);
        }
        // output store: normal cached path (nobody reads it; L2 writes back lazily)
        if (mc == 0) {
            *(float4*)(out + ((size_t)b * T_STEPS + t) * DRES + row0) =
                make_float4(x[0], x[1], x[2], x[3]);
        }

        ucur = unext;
    }
}

extern "C" void kernel_launch(void* const* d_in, const int* in_sizes, int n_in,
                              void* d_out, int out_size, void* d_ws, size_t ws_size,
                              hipStream_t stream) {
    const float* u      = (const float*)d_in[0];
    const float* w_in   = (const float*)d_in[1];
    const float* w      = (const float*)d_in[2];
    const float* w_bias = (const float*)d_in[3];
    float* out = (float*)d_out;
    u64* hbuf = (u64*)d_ws;

    // tags must start below 1 (ws is re-poisoned before every call)
    hipMemsetAsync(hbuf, 0, HBUF_BYTES, stream);

    esn_kernel<<<NB * 32, NTHREADS, 0, stream>>>(u, w_in, w, w_bias, out, hbuf);
}